// Round 8
// baseline (165.125 us; speedup 1.0000x reference)
//
#include <hip/hip_runtime.h>

typedef _Float16 half_t;
typedef __attribute__((ext_vector_type(8))) _Float16 half8;
typedef __attribute__((ext_vector_type(4))) _Float16 half4;
typedef __attribute__((ext_vector_type(4))) float f32x4;
typedef __attribute__((ext_vector_type(16))) float f32x16;

#define TSEQ   2048
#define DMODEL 1024
#define K2LOG  0.18033688011116016f   /* 0.125 * log2(e) */
#define DEFER_THR 8.0f

#if __has_builtin(__builtin_amdgcn_exp2f)
#define EXP2F(x) __builtin_amdgcn_exp2f(x)
#else
#define EXP2F(x) __expf(0.6931471805599453f * (x))
#endif

__device__ inline unsigned pk2(float a, float b) {
  auto h = __builtin_amdgcn_cvt_pkrtz(a, b);   // __fp16 ext_vector(2)
  return __builtin_bit_cast(unsigned, h);
}
__device__ inline half8 frag_from(unsigned a, unsigned b, unsigned c, unsigned d) {
  int4 t; t.x = (int)a; t.y = (int)b; t.z = (int)c; t.w = (int)d;
  return __builtin_bit_cast(half8, t);
}

// lane<32 <-> lane>=32 pairwise swap of two words:
// post: a = {a_lo, b_lo}, b = {a_hi, b_hi}
#if __has_builtin(__builtin_amdgcn_permlane32_swap)
__device__ inline void pl32(unsigned &a, unsigned &b) {
  auto r = __builtin_amdgcn_permlane32_swap(a, b, false, false);
  a = (unsigned)r[0]; b = (unsigned)r[1];
}
#else
__device__ inline void pl32(unsigned &a, unsigned &b) {
  const int hi = (threadIdx.x & 63) >> 5;
  unsigned sa = __shfl_xor(a, 32), sb = __shfl_xor(b, 32);
  unsigned na = hi ? sb : a;
  unsigned nb = hi ? b : sa;
  a = na; b = nb;
}
#endif
__device__ inline float partner32(float v, int hi) {
  unsigned a = __builtin_bit_cast(unsigned, v), b = a;
  pl32(a, b);                    // a = {v_lo,v_lo}, b = {v_hi,v_hi}
  return __builtin_bit_cast(float, hi ? a : b);
}

// ================== async global->LDS staging ==================
#define GLD_LDS(g, l) \
  __builtin_amdgcn_global_load_lds((const __attribute__((address_space(1))) void*)(g), \
                                   (__attribute__((address_space(3))) void*)(l), 16, 0, 0)

// ---------- W transpose + cast (both weights in one launch) ----------
__global__ void k_transpose_cast(const float* __restrict__ wqkv, half_t* __restrict__ wqt,
                                 const float* __restrict__ wproj, half_t* __restrict__ wpt) {
  __shared__ float tile[32][33];
  const int bx = blockIdx.x;
  const float* in;
  half_t* out;
  int n0, N;
  if (bx < 96) { in = wqkv; out = wqt; n0 = bx * 32; N = 3072; }
  else         { in = wproj; out = wpt; n0 = (bx - 96) * 32; N = 1024; }
  int k0 = blockIdx.y * 32;
  int tx = threadIdx.x, ty = threadIdx.y;   // block (32, 8)
#pragma unroll
  for (int i = 0; i < 32; i += 8)
    tile[ty + i][tx] = in[(size_t)(k0 + ty + i) * N + n0 + tx];
  __syncthreads();
#pragma unroll
  for (int i = 0; i < 32; i += 8)
    out[(size_t)(n0 + ty + i) * 1024 + k0 + tx] = (half_t)tile[tx][ty + i];
}

// ---------- LayerNorm: x [4096][1024] f32 -> xn f16 ----------
__global__ void k_layernorm(const float* __restrict__ x, const float* __restrict__ gamma,
                            const float* __restrict__ beta, half_t* __restrict__ xn) {
  int row = blockIdx.x, t = threadIdx.x;   // 256 threads, 4 elems each
  const float4 v = *(const float4*)(x + (size_t)row * DMODEL + t * 4);
  float s  = v.x + v.y + v.z + v.w;
  float ss = v.x * v.x + v.y * v.y + v.z * v.z + v.w * v.w;
#pragma unroll
  for (int off = 32; off >= 1; off >>= 1) {
    s  += __shfl_down(s, off);
    ss += __shfl_down(ss, off);
  }
  __shared__ float red[8];
  int wid = t >> 6;
  if ((t & 63) == 0) { red[wid] = s; red[4 + wid] = ss; }
  __syncthreads();
  s  = red[0] + red[1] + red[2] + red[3];
  ss = red[4] + red[5] + red[6] + red[7];
  float mu   = s * (1.f / DMODEL);
  float var  = ss * (1.f / DMODEL) - mu * mu;
  float rstd = rsqrtf(var + 1e-5f);
  float4 g = *(const float4*)(gamma + t * 4);
  float4 b = *(const float4*)(beta  + t * 4);
  half4 o;
  o.x = (half_t)((v.x - mu) * rstd * g.x + b.x);
  o.y = (half_t)((v.y - mu) * rstd * g.y + b.y);
  o.z = (half_t)((v.z - mu) * rstd * g.z + b.z);
  o.w = (half_t)((v.w - mu) * rstd * g.w + b.w);
  *(half4*)(xn + (size_t)row * DMODEL + t * 4) = o;
}

// ---------- QKV GEMM: double-buffered LDS prefetch ----------
__global__ __launch_bounds__(256, 3) void k_gemm_qkv(
    const half_t* __restrict__ A,   // xn [4096][1024]
    const half_t* __restrict__ Bt,  // Wqkv^T [3072][1024]
    const float* __restrict__ bias, // [3072]
    half_t* __restrict__ qh, half_t* __restrict__ kh, half_t* __restrict__ vt) {
  __shared__ __align__(16) char As[16384];   // 2 x 8KB
  __shared__ __align__(16) char Bs[16384];
  int mt = blockIdx.y, nt = blockIdx.x;
  int tid = threadIdx.x, lane = tid & 63, wid = tid >> 6;
  int wm = (wid >> 1) * 64, wn = (wid & 1) * 64;
  int col = lane & 15, kg = lane >> 4;
  f32x4 acc[4][4];
#pragma unroll
  for (int i = 0; i < 4; i++)
#pragma unroll
    for (int j = 0; j < 4; j++) acc[i][j] = f32x4{0.f, 0.f, 0.f, 0.f};

  const char* Ab = (const char*)(A  + (size_t)(mt * 128) * 1024);
  const char* Bb = (const char*)(Bt + (size_t)(nt * 128) * 1024);
  const int srow0 = wid * 32 + (lane >> 2);
  const int srow1 = srow0 + 16;
  const int sc0 = ((lane & 3) ^ ((srow0 >> 1) & 3)) << 4;
  const int sc1 = ((lane & 3) ^ ((srow1 >> 1) & 3)) << 4;
  const size_t go0 = (size_t)srow0 * 2048 + sc0;
  const size_t go1 = (size_t)srow1 * 2048 + sc1;
  const int lb0 = wid * 2048, lb1 = wid * 2048 + 1024;

  auto stage = [&](int kk, int b) {
    const size_t ko = (size_t)kk * 64;
    const int bo = b * 8192;
    GLD_LDS(Ab + go0 + ko, As + bo + lb0);
    GLD_LDS(Ab + go1 + ko, As + bo + lb1);
    GLD_LDS(Bb + go0 + ko, Bs + bo + lb0);
    GLD_LDS(Bb + go1 + ko, Bs + bo + lb1);
  };

  stage(0, 0);
  __syncthreads();

  for (int kk = 0; kk < 32; kk++) {
    const int cur = kk & 1;
    if (kk < 31) stage(kk + 1, cur ^ 1);
    const char* Ac = As + cur * 8192;
    const char* Bc = Bs + cur * 8192;
    half8 af[4], bf[4];
#pragma unroll
    for (int i = 0; i < 4; i++) {
      int r = wm + i * 16 + col;
      af[i] = *(const half8*)(Ac + r * 64 + ((kg ^ ((r >> 1) & 3)) << 4));
    }
#pragma unroll
    for (int j = 0; j < 4; j++) {
      int r = wn + j * 16 + col;
      bf[j] = *(const half8*)(Bc + r * 64 + ((kg ^ ((r >> 1) & 3)) << 4));
    }
    __builtin_amdgcn_s_setprio(1);
#pragma unroll
    for (int i = 0; i < 4; i++)
#pragma unroll
      for (int j = 0; j < 4; j++)
        acc[i][j] = __builtin_amdgcn_mfma_f32_16x16x32_f16(af[i], bf[j], acc[i][j], 0, 0, 0);
    __builtin_amdgcn_s_setprio(0);
    __syncthreads();
  }
#pragma unroll
  for (int i = 0; i < 4; i++)
#pragma unroll
    for (int j = 0; j < 4; j++) {
      int n = nt * 128 + wn + j * 16 + col;
      float bv = bias[n];
      int sec = n >> 10, d1 = n & 1023, head = d1 >> 6, dd = d1 & 63;
#pragma unroll
      for (int r = 0; r < 4; r++) {
        int m = mt * 128 + wm + i * 16 + kg * 4 + r;
        int b = m >> 11, t = m & 2047;
        half_t hv = (half_t)(acc[i][j][r] + bv);
        int bh = b * 16 + head;
        if (sec == 0)      qh[((size_t)bh * TSEQ + t) * 64 + dd] = hv;
        else if (sec == 1) kh[((size_t)bh * TSEQ + t) * 64 + dd] = hv;
        else               vt[((size_t)bh * 64 + dd) * TSEQ + t] = hv;
      }
    }
}

// ---------- fused flash attention: split-K + pipelined QK(t+1) || softmax(t) ----------
// Block: 8 waves = 512 thr. Waves 0-3: keys [0,1024); waves 4-7: [1024,2048).
// Two score register sets (sa,sb): QK of tile t+1 issues before softmax of tile t,
// so MFMA latency hides under the softmax VALU chain. Buffer hazards:
//   iter t (parity P=t&1): QK(t+1) reads K[P^1]; stage_K(t+2)->K[P];
//   PV(t) reads V[P]; stage_V(t+1)->V[P^1]; one barrier per tile.
__global__ __launch_bounds__(512, 4) void k_attn(
    const half_t* __restrict__ qh, const half_t* __restrict__ kh,
    const half_t* __restrict__ vt, half_t* __restrict__ ctx) {
  extern __shared__ __align__(16) char smem[];   // 64 KB
  const int bh = blockIdx.y, qt = blockIdx.x;
  const int tid = threadIdx.x, lane = tid & 63, wid = tid >> 6;   // 0..7
  const int l31 = lane & 31, hi = lane >> 5;
  const int khalf = wid >> 2;         // key half
  const int wq = wid & 3;             // q sub-block

  const int q = qt * 128 + wq * 32 + l31;
  const half_t* qbase = qh + ((size_t)bh * TSEQ + q) * 64 + hi * 8;
  half8 qf[4];
#pragma unroll
  for (int kc = 0; kc < 4; kc++) qf[kc] = *(const half8*)(qbase + kc * 16);

  f32x16 o0, o1, sa0, sa1, sb0, sb1;
#pragma unroll
  for (int r = 0; r < 16; r++) { o0[r] = 0.f; o1[r] = 0.f; }
  float m_run = -1e30f, l_run = 0.f;

  const char* kgb = (const char*)kh + (size_t)bh * 262144 + (size_t)khalf * 131072;
  const char* vgb = (const char*)vt + (size_t)bh * 262144 + khalf * 2048;
  char* sbK = smem + khalf * 32768;
  char* sbV = sbK + 16384;
  const int s7 = lane & 7;
  const int rA = wq * 16 + (lane >> 3);
  const int rB = rA + 8;
  const int gK0 = rA * 128  + ((s7 ^ (rA & 7)) << 4);
  const int gK1 = rB * 128  + ((s7 ^ (rB & 7)) << 4);
  const int gV0 = rA * 4096 + ((s7 ^ (rA & 7)) << 4);
  const int gV1 = rB * 4096 + ((s7 ^ (rB & 7)) << 4);
  const int lds0 = wq * 2048, lds1 = wq * 2048 + 1024;

#define STAGE_K(j, P) do {                                            \
    GLD_LDS(kgb + (size_t)(j) * 8192 + gK0, sbK + (P) * 8192 + lds0); \
    GLD_LDS(kgb + (size_t)(j) * 8192 + gK1, sbK + (P) * 8192 + lds1); \
  } while (0)
#define STAGE_V(j, P) do {                                            \
    GLD_LDS(vgb + (size_t)(j) * 128 + gV0, sbV + (P) * 8192 + lds0);  \
    GLD_LDS(vgb + (size_t)(j) * 128 + gV1, sbV + (P) * 8192 + lds1);  \
  } while (0)

  const int swr = (l31 & 7) << 4;
  const int rb  = l31 * 128;
  const int hb  = hi * 16;

#define QK_T(P, d0, d1) do {                                          \
    const char* lk_ = sbK + (P) * 8192;                               \
    __builtin_amdgcn_s_setprio(1);                                    \
    _Pragma("unroll")                                                 \
    for (int kc_ = 0; kc_ < 4; kc_++) {                               \
      const int off_ = (kc_ * 32 + hb) ^ swr;                         \
      half8 kf0_ = *(const half8*)(lk_ + rb + off_);                  \
      half8 kf1_ = *(const half8*)(lk_ + rb + 4096 + off_);           \
      d0 = __builtin_amdgcn_mfma_f32_32x32x16_f16(kf0_, qf[kc_], d0, 0, 0, 0); \
      d1 = __builtin_amdgcn_mfma_f32_32x32x16_f16(kf1_, qf[kc_], d1, 0, 0, 0); \
    }                                                                 \
    __builtin_amdgcn_s_setprio(0);                                    \
  } while (0)

#define SMAX(c0, c1) do {                                             \
    float m8[8];                                                      \
    _Pragma("unroll")                                                 \
    for (int r_ = 0; r_ < 8; r_++)                                    \
      m8[r_] = fmaxf(fmaxf(c0[r_], c0[r_ + 8]), fmaxf(c1[r_], c1[r_ + 8])); \
    _Pragma("unroll")                                                 \
    for (int r_ = 0; r_ < 4; r_++) m8[r_] = fmaxf(m8[r_], m8[r_ + 4]);\
    float mx_ = fmaxf(fmaxf(m8[0], m8[1]), fmaxf(m8[2], m8[3]));      \
    mx_ = fmaxf(mx_, partner32(mx_, hi));                             \
    float mx2_ = mx_ * K2LOG;                                         \
    if (__any(mx2_ > m_run + DEFER_THR)) {                            \
      float mn_  = fmaxf(m_run, mx2_);                                \
      float fac_ = EXP2F(m_run - mn_);                                \
      _Pragma("unroll")                                               \
      for (int r_ = 0; r_ < 16; r_++) { o0[r_] *= fac_; o1[r_] *= fac_; } \
      l_run *= fac_;                                                  \
      m_run = mn_;                                                    \
    }                                                                 \
    _Pragma("unroll")                                                 \
    for (int r_ = 0; r_ < 16; r_++) c0[r_] = EXP2F(fmaf(c0[r_], K2LOG, -m_run)); \
    _Pragma("unroll")                                                 \
    for (int r_ = 0; r_ < 16; r_++) c1[r_] = EXP2F(fmaf(c1[r_], K2LOG, -m_run)); \
    float s8[8];                                                      \
    _Pragma("unroll")                                                 \
    for (int r_ = 0; r_ < 8; r_++)                                    \
      s8[r_] = (c0[r_] + c0[r_ + 8]) + (c1[r_] + c1[r_ + 8]);         \
    _Pragma("unroll")                                                 \
    for (int r_ = 0; r_ < 4; r_++) s8[r_] += s8[r_ + 4];              \
    float sum_ = (s8[0] + s8[1]) + (s8[2] + s8[3]);                   \
    sum_ += partner32(sum_, hi);                                      \
    l_run += sum_;                                                    \
    {                                                                 \
      unsigned x0 = pk2(c0[0],  c0[1]),  x1 = pk2(c0[2],  c0[3]);     \
      unsigned z0 = pk2(c0[4],  c0[5]),  z1 = pk2(c0[6],  c0[7]);     \
      pl32(x0, z0); pl32(x1, z1);                                     \
      pf[0] = frag_from(x0, x1, z0, z1);                              \
      unsigned x2 = pk2(c0[8],  c0[9]),  x3 = pk2(c0[10], c0[11]);    \
      unsigned z2 = pk2(c0[12], c0[13]), z3 = pk2(c0[14], c0[15]);    \
      pl32(x2, z2); pl32(x3, z3);                                     \
      pf[1] = frag_from(x2, x3, z2, z3);                              \
    }                                                                 \
    {                                                                 \
      unsigned x0 = pk2(c1[0],  c1[1]),  x1 = pk2(c1[2],  c1[3]);     \
      unsigned z0 = pk2(c1[4],  c1[5]),  z1 = pk2(c1[6],  c1[7]);     \
      pl32(x0, z0); pl32(x1, z1);                                     \
      pf[2] = frag_from(x0, x1, z0, z1);                              \
      unsigned x2 = pk2(c1[8],  c1[9]),  x3 = pk2(c1[10], c1[11]);    \
      unsigned z2 = pk2(c1[12], c1[13]), z3 = pk2(c1[14], c1[15]);    \
      pl32(x2, z2); pl32(x3, z3);                                     \
      pf[3] = frag_from(x2, x3, z2, z3);                              \
    }                                                                 \
  } while (0)

#define PV_T(P) do {                                                  \
    const char* lv_ = sbV + (P) * 8192;                               \
    __builtin_amdgcn_s_setprio(1);                                    \
    _Pragma("unroll")                                                 \
    for (int kc_ = 0; kc_ < 4; kc_++) {                               \
      const int off_ = (kc_ * 32 + hb) ^ swr;                         \
      half8 vf0_ = *(const half8*)(lv_ + rb + off_);                  \
      half8 vf1_ = *(const half8*)(lv_ + rb + 4096 + off_);           \
      o0 = __builtin_amdgcn_mfma_f32_32x32x16_f16(vf0_, pf[kc_], o0, 0, 0, 0); \
      o1 = __builtin_amdgcn_mfma_f32_32x32x16_f16(vf1_, pf[kc_], o1, 0, 0, 0); \
    }                                                                 \
    __builtin_amdgcn_s_setprio(0);                                    \
  } while (0)

#define ITER(T, P, c0, c1, n0, n1) do {                               \
    if ((T) < 15) {                                                   \
      _Pragma("unroll")                                               \
      for (int r_ = 0; r_ < 16; r_++) { n0[r_] = 0.f; n1[r_] = 0.f; } \
      QK_T((P) ^ 1, n0, n1);                                          \
    }                                                                 \
    if ((T) < 14) STAGE_K((T) + 2, (P));                              \
    half8 pf[4];                                                      \
    SMAX(c0, c1);                                                     \
    PV_T((P));                                                        \
    if ((T) < 15) STAGE_V((T) + 1, (P) ^ 1);                          \
    __syncthreads();                                                  \
  } while (0)

  // prologue: K0,V0 staged; QK(0); K1 staged.
  STAGE_K(0, 0);
  STAGE_V(0, 0);
  __syncthreads();
#pragma unroll
  for (int r = 0; r < 16; r++) { sa0[r] = 0.f; sa1[r] = 0.f; }
  QK_T(0, sa0, sa1);
  STAGE_K(1, 1);
  __syncthreads();

#pragma unroll 1
  for (int t = 0; t < 16; t += 2) {
    ITER(t,     0, sa0, sa1, sb0, sb1);
    ITER(t + 1, 1, sb0, sb1, sa0, sa1);
  }

  // ---- cross-half merge via LDS (reuses K/V space; all compute done) ----
  float* ob = (float*)smem + wq * 2048;           // [32 regs][64 lanes]
  float* ml = (float*)(smem + 32768) + wq * 128;  // [2][64]
  if (khalf == 1) {
#pragma unroll
    for (int r = 0; r < 16; r++) {
      ob[r * 64 + lane]        = o0[r];
      ob[(r + 16) * 64 + lane] = o1[r];
    }
    ml[lane]      = m_run;
    ml[64 + lane] = l_run;
  }
  __syncthreads();
  if (khalf == 0) {
    float m2 = ml[lane], l2 = ml[64 + lane];
    float mN = fmaxf(m_run, m2);
    float fa = EXP2F(m_run - mN), fb = EXP2F(m2 - mN);
    float lT = l_run * fa + l2 * fb;
    const float inv = 1.f / fmaxf(lT, 1e-12f);
    const int b = bh >> 4, h = bh & 15;
    half_t* cbp = ctx + ((size_t)(b * TSEQ + q)) * DMODEL + h * 64 + hi * 4;
#pragma unroll
    for (int g = 0; g < 4; g++) {
      half4 h0, h1;
#pragma unroll
      for (int j = 0; j < 4; j++) {
        float v0 = o0[4 * g + j] * fa + ob[(4 * g + j) * 64 + lane] * fb;
        float v1 = o1[4 * g + j] * fa + ob[(16 + 4 * g + j) * 64 + lane] * fb;
        h0[j] = (half_t)(v0 * inv);
        h1[j] = (half_t)(v1 * inv);
      }
      *(half4*)(cbp + 8 * g)      = h0;
      *(half4*)(cbp + 32 + 8 * g) = h1;
    }
  }
#undef STAGE_K
#undef STAGE_V
#undef QK_T
#undef SMAX
#undef PV_T
#undef ITER
}

// ---------- output projection: 128x64 tile, 512 blocks (2/CU) ----------
__global__ __launch_bounds__(256, 4) void k_gemm_proj(
    const half_t* __restrict__ A,   // ctx [4096][1024]
    const half_t* __restrict__ Bt,  // Wproj^T [1024][1024]
    const float* __restrict__ bias, float* __restrict__ out) {
  __shared__ __align__(16) char As[16384];  // 2 x 8KB (128 rows x 64B)
  __shared__ __align__(16) char Bs[8192];   // 2 x 4KB (64 rows x 64B)
  int mt = blockIdx.y, nt = blockIdx.x;
  int tid = threadIdx.x, lane = tid & 63, wid = tid >> 6;
  int wm = (wid >> 1) * 64, wn = (wid & 1) * 32;
  int col = lane & 15, kg = lane >> 4;
  f32x4 acc[4][2];
#pragma unroll
  for (int i = 0; i < 4; i++)
#pragma unroll
    for (int j = 0; j < 2; j++) acc[i][j] = f32x4{0.f, 0.f, 0.f, 0.f};

  const char* Ab = (const char*)(A  + (size_t)(mt * 128) * 1024);
  const char* Bb = (const char*)(Bt + (size_t)(nt * 64) * 1024);
  const int srow0 = wid * 32 + (lane >> 2);
  const int srow1 = srow0 + 16;
  const int sc0 = ((lane & 3) ^ ((srow0 >> 1) & 3)) << 4;
  const int sc1 = ((lane & 3) ^ ((srow1 >> 1) & 3)) << 4;
  const size_t goA0 = (size_t)srow0 * 2048 + sc0;
  const size_t goA1 = (size_t)srow1 * 2048 + sc1;
  const int lbA0 = wid * 2048, lbA1 = wid * 2048 + 1024;
  const int brow = tid >> 2;
  const int bcs = ((lane & 3) ^ ((brow >> 1) & 3)) << 4;
  const size_t goB = (size_t)brow * 2048 + bcs;
  const int lbB = wid * 1024;

  auto stage = [&](int kk, int b) {
    const size_t ko = (size_t)kk * 64;
    GLD_LDS(Ab + goA0 + ko, As + b * 8192 + lbA0);
    GLD_LDS(Ab + goA1 + ko, As + b * 8192 + lbA1);
    GLD_LDS(Bb + goB  + ko, Bs + b * 4096 + lbB);
  };

  stage(0, 0);
  __syncthreads();

  for (int kk = 0; kk < 32; kk++) {
    const int cur = kk & 1;
    if (kk < 31) stage(kk + 1, cur ^ 1);
    const char* Ac = As + cur * 8192;
    const char* Bc = Bs + cur * 4096;
    half8 af[4], bf[2];
#pragma unroll
    for (int i = 0; i < 4; i++) {
      int r = wm + i * 16 + col;
      af[i] = *(const half8*)(Ac + r * 64 + ((kg ^ ((r >> 1) & 3)) << 4));
    }
#pragma unroll
    for (int j = 0; j < 2; j++) {
      int r = wn + j * 16 + col;
      bf[j] = *(const half8*)(Bc + r * 64 + ((kg ^ ((r >> 1) & 3)) << 4));
    }
    __builtin_amdgcn_s_setprio(1);
#pragma unroll
    for (int i = 0; i < 4; i++)
#pragma unroll
      for (int j = 0; j < 2; j++)
        acc[i][j] = __builtin_amdgcn_mfma_f32_16x16x32_f16(af[i], bf[j], acc[i][j], 0, 0, 0);
    __builtin_amdgcn_s_setprio(0);
    __syncthreads();
  }
#pragma unroll
  for (int i = 0; i < 4; i++)
#pragma unroll
    for (int j = 0; j < 2; j++) {
      int n = nt * 64 + wn + j * 16 + col;
      float bv = bias[n];
#pragma unroll
      for (int r = 0; r < 4; r++) {
        int m = mt * 128 + wm + i * 16 + kg * 4 + r;
        out[(size_t)m * DMODEL + n] = acc[i][j][r] + bv;
      }
    }
}

extern "C" void kernel_launch(void* const* d_in, const int* in_sizes, int n_in,
                              void* d_out, int out_size, void* d_ws, size_t ws_size,
                              hipStream_t stream) {
  const float* x     = (const float*)d_in[0];
  const float* gamma = (const float*)d_in[1];
  const float* beta  = (const float*)d_in[2];
  const float* Wqkv  = (const float*)d_in[3];
  const float* bqkv  = (const float*)d_in[4];
  const float* Wproj = (const float*)d_in[5];
  const float* bproj = (const float*)d_in[6];
  float* out = (float*)d_out;

  char* ws = (char*)d_ws;              // 48 MB used
  half_t* xn  = (half_t*)(ws);                       // 8 MB
  half_t* wqt = (half_t*)(ws + ((size_t)8  << 20));  // 6 MB
  half_t* wpt = (half_t*)(ws + ((size_t)14 << 20));  // 2 MB
  half_t* qh  = (half_t*)(ws + ((size_t)16 << 20));  // 8 MB
  half_t* kh  = (half_t*)(ws + ((size_t)24 << 20));  // 8 MB
  half_t* vt  = (half_t*)(ws + ((size_t)32 << 20));  // 8 MB
  half_t* ctx = (half_t*)(ws + ((size_t)40 << 20));  // 8 MB

  k_transpose_cast<<<dim3(128, 32), dim3(32, 8), 0, stream>>>(Wqkv, wqt, Wproj, wpt);
  k_layernorm<<<4096, 256, 0, stream>>>(x, gamma, beta, xn);
  k_gemm_qkv<<<dim3(24, 32), 256, 0, stream>>>(xn, wqt, bqkv, qh, kh, vt);
  k_attn<<<dim3(16, 32), 512, 65536, stream>>>(qh, kh, vt, ctx);
  k_gemm_proj<<<dim3(16, 32), 256, 0, stream>>>(ctx, wpt, bproj, out);
}

// Round 9
// 124.197 us; speedup vs baseline: 1.3295x; 1.3295x over previous
//
#include <hip/hip_runtime.h>

typedef _Float16 half_t;
typedef __attribute__((ext_vector_type(8))) _Float16 half8;
typedef __attribute__((ext_vector_type(4))) _Float16 half4;
typedef __attribute__((ext_vector_type(4))) float f32x4;
typedef __attribute__((ext_vector_type(16))) float f32x16;

#define TSEQ   2048
#define DMODEL 1024
#define K2LOG  0.18033688011116016f   /* 0.125 * log2(e) */
#define DEFER_THR 8.0f

#if __has_builtin(__builtin_amdgcn_exp2f)
#define EXP2F(x) __builtin_amdgcn_exp2f(x)
#else
#define EXP2F(x) __expf(0.6931471805599453f * (x))
#endif

__device__ inline unsigned pk2(float a, float b) {
  auto h = __builtin_amdgcn_cvt_pkrtz(a, b);   // __fp16 ext_vector(2)
  return __builtin_bit_cast(unsigned, h);
}
__device__ inline half8 frag_from(unsigned a, unsigned b, unsigned c, unsigned d) {
  int4 t; t.x = (int)a; t.y = (int)b; t.z = (int)c; t.w = (int)d;
  return __builtin_bit_cast(half8, t);
}

// lane<32 <-> lane>=32 pairwise swap of two words:
// post: a = {a_lo, b_lo}, b = {a_hi, b_hi}
#if __has_builtin(__builtin_amdgcn_permlane32_swap)
__device__ inline void pl32(unsigned &a, unsigned &b) {
  auto r = __builtin_amdgcn_permlane32_swap(a, b, false, false);
  a = (unsigned)r[0]; b = (unsigned)r[1];
}
#else
__device__ inline void pl32(unsigned &a, unsigned &b) {
  const int hi = (threadIdx.x & 63) >> 5;
  unsigned sa = __shfl_xor(a, 32), sb = __shfl_xor(b, 32);
  unsigned na = hi ? sb : a;
  unsigned nb = hi ? b : sa;
  a = na; b = nb;
}
#endif
__device__ inline float partner32(float v, int hi) {
  unsigned a = __builtin_bit_cast(unsigned, v), b = a;
  pl32(a, b);                    // a = {v_lo,v_lo}, b = {v_hi,v_hi}
  return __builtin_bit_cast(float, hi ? a : b);
}

// ================== async global->LDS staging ==================
#define GLD_LDS(g, l) \
  __builtin_amdgcn_global_load_lds((const __attribute__((address_space(1))) void*)(g), \
                                   (__attribute__((address_space(3))) void*)(l), 16, 0, 0)

// ---------- fused prep: LN (blocks 0..4095) + W transposes (blocks 4096..8191) ----------
__global__ void k_prep(const float* __restrict__ x, const float* __restrict__ gamma,
                       const float* __restrict__ beta, half_t* __restrict__ xn,
                       const float* __restrict__ wqkv, half_t* __restrict__ wqt,
                       const float* __restrict__ wproj, half_t* __restrict__ wpt) {
  __shared__ float sm[32 * 33];
  const int blk = blockIdx.x;
  if (blk < 4096) {
    // ---- LayerNorm row ----
    int row = blk, t = threadIdx.x;   // 256 threads, 4 elems each
    const float4 v = *(const float4*)(x + (size_t)row * DMODEL + t * 4);
    float s  = v.x + v.y + v.z + v.w;
    float ss = v.x * v.x + v.y * v.y + v.z * v.z + v.w * v.w;
#pragma unroll
    for (int off = 32; off >= 1; off >>= 1) {
      s  += __shfl_down(s, off);
      ss += __shfl_down(ss, off);
    }
    int wid = t >> 6;
    if ((t & 63) == 0) { sm[wid] = s; sm[4 + wid] = ss; }
    __syncthreads();
    s  = sm[0] + sm[1] + sm[2] + sm[3];
    ss = sm[4] + sm[5] + sm[6] + sm[7];
    float mu   = s * (1.f / DMODEL);
    float var  = ss * (1.f / DMODEL) - mu * mu;
    float rstd = rsqrtf(var + 1e-5f);
    float4 g = *(const float4*)(gamma + t * 4);
    float4 b = *(const float4*)(beta  + t * 4);
    half4 o;
    o.x = (half_t)((v.x - mu) * rstd * g.x + b.x);
    o.y = (half_t)((v.y - mu) * rstd * g.y + b.y);
    o.z = (half_t)((v.z - mu) * rstd * g.z + b.z);
    o.w = (half_t)((v.w - mu) * rstd * g.w + b.w);
    *(half4*)(xn + (size_t)row * DMODEL + t * 4) = o;
  } else {
    // ---- W transpose + cast: in [K=1024][N] f32 -> out [N][1024] f16 ----
    const int bx2 = blk - 4096;
    const int bx = bx2 & 127, by = bx2 >> 7;
    const float* in;
    half_t* out;
    int n0, N;
    if (bx < 96) { in = wqkv; out = wqt; n0 = bx * 32; N = 3072; }
    else         { in = wproj; out = wpt; n0 = (bx - 96) * 32; N = 1024; }
    int k0 = by * 32;
    int tx = threadIdx.x & 31, ty = threadIdx.x >> 5;  // (32, 8)
#pragma unroll
    for (int i = 0; i < 32; i += 8)
      sm[(ty + i) * 33 + tx] = in[(size_t)(k0 + ty + i) * N + n0 + tx];
    __syncthreads();
#pragma unroll
    for (int i = 0; i < 32; i += 8)
      out[(size_t)(n0 + ty + i) * 1024 + k0 + tx] = (half_t)sm[tx * 33 + ty + i];
  }
}

// ---------- QKV GEMM: double-buffered LDS prefetch ----------
__global__ __launch_bounds__(256, 4) void k_gemm_qkv(
    const half_t* __restrict__ A,   // xn [4096][1024]
    const half_t* __restrict__ Bt,  // Wqkv^T [3072][1024]
    const float* __restrict__ bias, // [3072]
    half_t* __restrict__ qh, half_t* __restrict__ kh, half_t* __restrict__ vt) {
  __shared__ __align__(16) char As[16384];   // 2 x 8KB
  __shared__ __align__(16) char Bs[16384];
  int mt = blockIdx.y, nt = blockIdx.x;
  int tid = threadIdx.x, lane = tid & 63, wid = tid >> 6;
  int wm = (wid >> 1) * 64, wn = (wid & 1) * 64;
  int col = lane & 15, kg = lane >> 4;
  f32x4 acc[4][4];
#pragma unroll
  for (int i = 0; i < 4; i++)
#pragma unroll
    for (int j = 0; j < 4; j++) acc[i][j] = f32x4{0.f, 0.f, 0.f, 0.f};

  const char* Ab = (const char*)(A  + (size_t)(mt * 128) * 1024);
  const char* Bb = (const char*)(Bt + (size_t)(nt * 128) * 1024);
  const int srow0 = wid * 32 + (lane >> 2);
  const int srow1 = srow0 + 16;
  const int sc0 = ((lane & 3) ^ ((srow0 >> 1) & 3)) << 4;
  const int sc1 = ((lane & 3) ^ ((srow1 >> 1) & 3)) << 4;
  const size_t go0 = (size_t)srow0 * 2048 + sc0;
  const size_t go1 = (size_t)srow1 * 2048 + sc1;
  const int lb0 = wid * 2048, lb1 = wid * 2048 + 1024;

  auto stage = [&](int kk, int b) {
    const size_t ko = (size_t)kk * 64;
    const int bo = b * 8192;
    GLD_LDS(Ab + go0 + ko, As + bo + lb0);
    GLD_LDS(Ab + go1 + ko, As + bo + lb1);
    GLD_LDS(Bb + go0 + ko, Bs + bo + lb0);
    GLD_LDS(Bb + go1 + ko, Bs + bo + lb1);
  };

  stage(0, 0);
  __syncthreads();

  for (int kk = 0; kk < 32; kk++) {
    const int cur = kk & 1;
    if (kk < 31) stage(kk + 1, cur ^ 1);
    const char* Ac = As + cur * 8192;
    const char* Bc = Bs + cur * 8192;
    half8 af[4], bf[4];
#pragma unroll
    for (int i = 0; i < 4; i++) {
      int r = wm + i * 16 + col;
      af[i] = *(const half8*)(Ac + r * 64 + ((kg ^ ((r >> 1) & 3)) << 4));
    }
#pragma unroll
    for (int j = 0; j < 4; j++) {
      int r = wn + j * 16 + col;
      bf[j] = *(const half8*)(Bc + r * 64 + ((kg ^ ((r >> 1) & 3)) << 4));
    }
    __builtin_amdgcn_s_setprio(1);
#pragma unroll
    for (int i = 0; i < 4; i++)
#pragma unroll
      for (int j = 0; j < 4; j++)
        acc[i][j] = __builtin_amdgcn_mfma_f32_16x16x32_f16(af[i], bf[j], acc[i][j], 0, 0, 0);
    __builtin_amdgcn_s_setprio(0);
    __syncthreads();
  }
#pragma unroll
  for (int i = 0; i < 4; i++)
#pragma unroll
    for (int j = 0; j < 4; j++) {
      int n = nt * 128 + wn + j * 16 + col;
      float bv = bias[n];
      int sec = n >> 10, d1 = n & 1023, head = d1 >> 6, dd = d1 & 63;
#pragma unroll
      for (int r = 0; r < 4; r++) {
        int m = mt * 128 + wm + i * 16 + kg * 4 + r;
        int b = m >> 11, t = m & 2047;
        half_t hv = (half_t)(acc[i][j][r] + bv);
        int bh = b * 16 + head;
        if (sec == 0)      qh[((size_t)bh * TSEQ + t) * 64 + dd] = hv;
        else if (sec == 1) kh[((size_t)bh * TSEQ + t) * 64 + dd] = hv;
        else               vt[((size_t)bh * 64 + dd) * TSEQ + t] = hv;
      }
    }
}

// ---------- fused flash attention, split-K, GLD_LDS staging, tree softmax ----------
// (round-7 verified structure: 53.2 us, no spill)
__global__ __launch_bounds__(512, 4) void k_attn(
    const half_t* __restrict__ qh, const half_t* __restrict__ kh,
    const half_t* __restrict__ vt, half_t* __restrict__ ctx) {
  extern __shared__ __align__(16) char smem[];   // 64 KB
  const int bh = blockIdx.y, qt = blockIdx.x;
  const int tid = threadIdx.x, lane = tid & 63, wid = tid >> 6;   // 0..7
  const int l31 = lane & 31, hi = lane >> 5;
  const int khalf = wid >> 2;         // key half
  const int wq = wid & 3;             // q sub-block

  const int q = qt * 128 + wq * 32 + l31;
  const half_t* qbase = qh + ((size_t)bh * TSEQ + q) * 64 + hi * 8;
  half8 qf[4];
#pragma unroll
  for (int kc = 0; kc < 4; kc++) qf[kc] = *(const half8*)(qbase + kc * 16);

  f32x16 o0, o1;
#pragma unroll
  for (int r = 0; r < 16; r++) { o0[r] = 0.f; o1[r] = 0.f; }
  float m_run = -1e30f, l_run = 0.f;

  const char* kgb = (const char*)kh + (size_t)bh * 262144 + (size_t)khalf * 131072;
  const char* vgb = (const char*)vt + (size_t)bh * 262144 + khalf * 2048;
  char* sbK = smem + khalf * 32768;
  char* sbV = sbK + 16384;
  const int s7 = lane & 7;
  const int rA = wq * 16 + (lane >> 3);
  const int rB = rA + 8;
  const size_t gK0 = (size_t)rA * 128  + ((s7 ^ (rA & 7)) << 4);
  const size_t gK1 = (size_t)rB * 128  + ((s7 ^ (rB & 7)) << 4);
  const size_t gV0 = (size_t)rA * 4096 + ((s7 ^ (rA & 7)) << 4);
  const size_t gV1 = (size_t)rB * 4096 + ((s7 ^ (rB & 7)) << 4);
  const int lds0 = wq * 2048, lds1 = wq * 2048 + 1024;

  auto stage = [&](int t) {
    const int buf = (t & 1) * 8192;
    GLD_LDS(kgb + (size_t)t * 8192 + gK0, sbK + buf + lds0);
    GLD_LDS(kgb + (size_t)t * 8192 + gK1, sbK + buf + lds1);
    GLD_LDS(vgb + (size_t)t * 128  + gV0, sbV + buf + lds0);
    GLD_LDS(vgb + (size_t)t * 128  + gV1, sbV + buf + lds1);
  };

  stage(0);
  __syncthreads();                       // drains vmcnt -> buf0 ready

  const int swr = (l31 & 7) << 4;        // frag-read swizzle
  const int rb  = l31 * 128;
  const int hb  = hi * 16;

  for (int t = 0; t < 16; ++t) {
    if (t < 15) stage(t + 1);            // lands by end-of-iter barrier
    const char* lk = sbK + (t & 1) * 8192;
    const char* lv = sbV + (t & 1) * 8192;

    // ---- S^T = K * Q^T ----
    f32x16 s0, s1;
#pragma unroll
    for (int r = 0; r < 16; r++) { s0[r] = 0.f; s1[r] = 0.f; }
    __builtin_amdgcn_s_setprio(1);
#pragma unroll
    for (int kc = 0; kc < 4; kc++) {
      const int off = (kc * 32 + hb) ^ swr;
      half8 kf0 = *(const half8*)(lk + rb + off);
      half8 kf1 = *(const half8*)(lk + rb + 4096 + off);
      s0 = __builtin_amdgcn_mfma_f32_32x32x16_f16(kf0, qf[kc], s0, 0, 0, 0);
      s1 = __builtin_amdgcn_mfma_f32_32x32x16_f16(kf1, qf[kc], s1, 0, 0, 0);
    }
    __builtin_amdgcn_s_setprio(0);

    // ---- online softmax, log2 domain, tree reductions ----
    float a16[16];
#pragma unroll
    for (int r = 0; r < 16; r++) a16[r] = fmaxf(s0[r], s1[r]);
#pragma unroll
    for (int r = 0; r < 8; r++) a16[r] = fmaxf(a16[r], a16[r + 8]);
#pragma unroll
    for (int r = 0; r < 4; r++) a16[r] = fmaxf(a16[r], a16[r + 4]);
    float mx = fmaxf(fmaxf(a16[0], a16[1]), fmaxf(a16[2], a16[3]));
    mx = fmaxf(mx, partner32(mx, hi));
    float mx2 = mx * K2LOG;
    if (__any(mx2 > m_run + DEFER_THR)) {
      float mn  = fmaxf(m_run, mx2);
      float fac = EXP2F(m_run - mn);
#pragma unroll
      for (int r = 0; r < 16; r++) { o0[r] *= fac; o1[r] *= fac; }
      l_run *= fac;
      m_run = mn;
    }
#pragma unroll
    for (int r = 0; r < 16; r++) s0[r] = EXP2F(fmaf(s0[r], K2LOG, -m_run));
#pragma unroll
    for (int r = 0; r < 16; r++) s1[r] = EXP2F(fmaf(s1[r], K2LOG, -m_run));
#pragma unroll
    for (int r = 0; r < 16; r++) a16[r] = s0[r] + s1[r];
#pragma unroll
    for (int r = 0; r < 8; r++) a16[r] += a16[r + 8];
#pragma unroll
    for (int r = 0; r < 4; r++) a16[r] += a16[r + 4];
    float sum = (a16[0] + a16[1]) + (a16[2] + a16[3]);
    sum += partner32(sum, hi);
    l_run += sum;

    // ---- P -> f16 B-fragments: pack + permlane32_swap ----
    half8 pf[4];
    {
      unsigned x0 = pk2(s0[0],  s0[1]),  x1 = pk2(s0[2],  s0[3]);
      unsigned z0 = pk2(s0[4],  s0[5]),  z1 = pk2(s0[6],  s0[7]);
      pl32(x0, z0); pl32(x1, z1);
      pf[0] = frag_from(x0, x1, z0, z1);
      unsigned x2 = pk2(s0[8],  s0[9]),  x3 = pk2(s0[10], s0[11]);
      unsigned z2 = pk2(s0[12], s0[13]), z3 = pk2(s0[14], s0[15]);
      pl32(x2, z2); pl32(x3, z3);
      pf[1] = frag_from(x2, x3, z2, z3);
    }
    {
      unsigned x0 = pk2(s1[0],  s1[1]),  x1 = pk2(s1[2],  s1[3]);
      unsigned z0 = pk2(s1[4],  s1[5]),  z1 = pk2(s1[6],  s1[7]);
      pl32(x0, z0); pl32(x1, z1);
      pf[2] = frag_from(x0, x1, z0, z1);
      unsigned x2 = pk2(s1[8],  s1[9]),  x3 = pk2(s1[10], s1[11]);
      unsigned z2 = pk2(s1[12], s1[13]), z3 = pk2(s1[14], s1[15]);
      pl32(x2, z2); pl32(x3, z3);
      pf[3] = frag_from(x2, x3, z2, z3);
    }

    // ---- O^T += V^T * P^T ----
    __builtin_amdgcn_s_setprio(1);
#pragma unroll
    for (int kc2 = 0; kc2 < 4; kc2++) {
      const int off = (kc2 * 32 + hb) ^ swr;
      half8 vf0 = *(const half8*)(lv + rb + off);
      half8 vf1 = *(const half8*)(lv + rb + 4096 + off);
      o0 = __builtin_amdgcn_mfma_f32_32x32x16_f16(vf0, pf[kc2], o0, 0, 0, 0);
      o1 = __builtin_amdgcn_mfma_f32_32x32x16_f16(vf1, pf[kc2], o1, 0, 0, 0);
    }
    __builtin_amdgcn_s_setprio(0);
    __syncthreads();
  }

  // ---- cross-half merge via LDS ----
  float* ob = (float*)smem + wq * 2048;           // [32 regs][64 lanes]
  float* ml = (float*)(smem + 32768) + wq * 128;  // [2][64]
  if (khalf == 1) {
#pragma unroll
    for (int r = 0; r < 16; r++) {
      ob[r * 64 + lane]        = o0[r];
      ob[(r + 16) * 64 + lane] = o1[r];
    }
    ml[lane]      = m_run;
    ml[64 + lane] = l_run;
  }
  __syncthreads();
  if (khalf == 0) {
    float m2 = ml[lane], l2 = ml[64 + lane];
    float mN = fmaxf(m_run, m2);
    float fa = EXP2F(m_run - mN), fb = EXP2F(m2 - mN);
    float lT = l_run * fa + l2 * fb;
    const float inv = 1.f / fmaxf(lT, 1e-12f);
    const int b = bh >> 4, h = bh & 15;
    half_t* cbp = ctx + ((size_t)(b * TSEQ + q)) * DMODEL + h * 64 + hi * 4;
#pragma unroll
    for (int g = 0; g < 4; g++) {
      half4 h0, h1;
#pragma unroll
      for (int j = 0; j < 4; j++) {
        float v0 = o0[4 * g + j] * fa + ob[(4 * g + j) * 64 + lane] * fb;
        float v1 = o1[4 * g + j] * fa + ob[(16 + 4 * g + j) * 64 + lane] * fb;
        h0[j] = (half_t)(v0 * inv);
        h1[j] = (half_t)(v1 * inv);
      }
      *(half4*)(cbp + 8 * g)      = h0;
      *(half4*)(cbp + 32 + 8 * g) = h1;
    }
  }
}

// ---------- output projection: 128x64 tile, 512 blocks (2/CU) ----------
__global__ __launch_bounds__(256, 4) void k_gemm_proj(
    const half_t* __restrict__ A,   // ctx [4096][1024]
    const half_t* __restrict__ Bt,  // Wproj^T [1024][1024]
    const float* __restrict__ bias, float* __restrict__ out) {
  __shared__ __align__(16) char As[16384];  // 2 x 8KB (128 rows x 64B)
  __shared__ __align__(16) char Bs[8192];   // 2 x 4KB (64 rows x 64B)
  int mt = blockIdx.y, nt = blockIdx.x;
  int tid = threadIdx.x, lane = tid & 63, wid = tid >> 6;
  int wm = (wid >> 1) * 64, wn = (wid & 1) * 32;
  int col = lane & 15, kg = lane >> 4;
  f32x4 acc[4][2];
#pragma unroll
  for (int i = 0; i < 4; i++)
#pragma unroll
    for (int j = 0; j < 2; j++) acc[i][j] = f32x4{0.f, 0.f, 0.f, 0.f};

  const char* Ab = (const char*)(A  + (size_t)(mt * 128) * 1024);
  const char* Bb = (const char*)(Bt + (size_t)(nt * 64) * 1024);
  const int srow0 = wid * 32 + (lane >> 2);
  const int srow1 = srow0 + 16;
  const int sc0 = ((lane & 3) ^ ((srow0 >> 1) & 3)) << 4;
  const int sc1 = ((lane & 3) ^ ((srow1 >> 1) & 3)) << 4;
  const size_t goA0 = (size_t)srow0 * 2048 + sc0;
  const size_t goA1 = (size_t)srow1 * 2048 + sc1;
  const int lbA0 = wid * 2048, lbA1 = wid * 2048 + 1024;
  const int brow = tid >> 2;
  const int bcs = ((lane & 3) ^ ((brow >> 1) & 3)) << 4;
  const size_t goB = (size_t)brow * 2048 + bcs;
  const int lbB = wid * 1024;

  auto stage = [&](int kk, int b) {
    const size_t ko = (size_t)kk * 64;
    GLD_LDS(Ab + goA0 + ko, As + b * 8192 + lbA0);
    GLD_LDS(Ab + goA1 + ko, As + b * 8192 + lbA1);
    GLD_LDS(Bb + goB  + ko, Bs + b * 4096 + lbB);
  };

  stage(0, 0);
  __syncthreads();

  for (int kk = 0; kk < 32; kk++) {
    const int cur = kk & 1;
    if (kk < 31) stage(kk + 1, cur ^ 1);
    const char* Ac = As + cur * 8192;
    const char* Bc = Bs + cur * 4096;
    half8 af[4], bf[2];
#pragma unroll
    for (int i = 0; i < 4; i++) {
      int r = wm + i * 16 + col;
      af[i] = *(const half8*)(Ac + r * 64 + ((kg ^ ((r >> 1) & 3)) << 4));
    }
#pragma unroll
    for (int j = 0; j < 2; j++) {
      int r = wn + j * 16 + col;
      bf[j] = *(const half8*)(Bc + r * 64 + ((kg ^ ((r >> 1) & 3)) << 4));
    }
    __builtin_amdgcn_s_setprio(1);
#pragma unroll
    for (int i = 0; i < 4; i++)
#pragma unroll
      for (int j = 0; j < 2; j++)
        acc[i][j] = __builtin_amdgcn_mfma_f32_16x16x32_f16(af[i], bf[j], acc[i][j], 0, 0, 0);
    __builtin_amdgcn_s_setprio(0);
    __syncthreads();
  }
#pragma unroll
  for (int i = 0; i < 4; i++)
#pragma unroll
    for (int j = 0; j < 2; j++) {
      int n = nt * 64 + wn + j * 16 + col;
      float bv = bias[n];
#pragma unroll
      for (int r = 0; r < 4; r++) {
        int m = mt * 128 + wm + i * 16 + kg * 4 + r;
        out[(size_t)m * DMODEL + n] = acc[i][j][r] + bv;
      }
    }
}

extern "C" void kernel_launch(void* const* d_in, const int* in_sizes, int n_in,
                              void* d_out, int out_size, void* d_ws, size_t ws_size,
                              hipStream_t stream) {
  const float* x     = (const float*)d_in[0];
  const float* gamma = (const float*)d_in[1];
  const float* beta  = (const float*)d_in[2];
  const float* Wqkv  = (const float*)d_in[3];
  const float* bqkv  = (const float*)d_in[4];
  const float* Wproj = (const float*)d_in[5];
  const float* bproj = (const float*)d_in[6];
  float* out = (float*)d_out;

  char* ws = (char*)d_ws;              // 48 MB used
  half_t* xn  = (half_t*)(ws);                       // 8 MB
  half_t* wqt = (half_t*)(ws + ((size_t)8  << 20));  // 6 MB
  half_t* wpt = (half_t*)(ws + ((size_t)14 << 20));  // 2 MB
  half_t* qh  = (half_t*)(ws + ((size_t)16 << 20));  // 8 MB
  half_t* kh  = (half_t*)(ws + ((size_t)24 << 20));  // 8 MB
  half_t* vt  = (half_t*)(ws + ((size_t)32 << 20));  // 8 MB
  half_t* ctx = (half_t*)(ws + ((size_t)40 << 20));  // 8 MB

  k_prep<<<8192, 256, 0, stream>>>(x, gamma, beta, xn, Wqkv, wqt, Wproj, wpt);
  k_gemm_qkv<<<dim3(24, 32), 256, 0, stream>>>(xn, wqt, bqkv, qh, kh, vt);
  k_attn<<<dim3(16, 32), 512, 65536, stream>>>(qh, kh, vt, ctx);
  k_gemm_proj<<<dim3(16, 32), 256, 0, stream>>>(ctx, wpt, bproj, out);
}